// Round 1
// 428.123 us; speedup vs baseline: 1.0599x; 1.0599x over previous
//
#include <hip/hip_runtime.h>
#include <hip/hip_bf16.h>

typedef __attribute__((ext_vector_type(8))) short bf16x8;   // 8 bf16 in 4 VGPRs
typedef __attribute__((ext_vector_type(4))) float f32x4;
typedef unsigned int uint32;

#define DMODEL 1024
#define SEQ    2048
#define NB     2
#define NH     16
#define HD     64
#define FDIM   4096
#define NTOK   (NB*SEQ)   // 4096

// ---------------- async global->LDS (wave-uniform LDS base + lane*16) ----------------
__device__ __forceinline__ void async16(const void* g, void* s) {
    __builtin_amdgcn_global_load_lds((const __attribute__((address_space(1))) unsigned int*)g,
                                     (__attribute__((address_space(3))) unsigned int*)s,
                                     16, 0, 0);
}

// ---------------- transpose + f32->bf16 convert: src[R][C] f32 -> dst[C][R] bf16 ----------------
__global__ __launch_bounds__(256) void transpose_cvt_k(const float* __restrict__ src,
                                                       __hip_bfloat16* __restrict__ dst,
                                                       int R, int C) {
    __shared__ __hip_bfloat16 tile[32][33];
    int tx = threadIdx.x, ty = threadIdx.y;
    int bx = blockIdx.x * 32, by = blockIdx.y * 32;
    for (int i = 0; i < 32; i += 8)
        tile[ty + i][tx] = __float2bfloat16(src[(size_t)(by + ty + i) * C + bx + tx]);
    __syncthreads();
    for (int i = 0; i < 32; i += 8)
        dst[(size_t)(bx + ty + i) * R + by + tx] = tile[tx][ty + i];
}

// ---------------- layernorm: f32 row of 1024, unbiased std (ddof=1), /(std+eps) -> bf16 ----------------
__global__ __launch_bounds__(256) void ln_kernel(const float* __restrict__ x,
                                                 const float* __restrict__ alpha,
                                                 const float* __restrict__ beta,
                                                 __hip_bfloat16* __restrict__ out) {
    const int row = blockIdx.x, tid = threadIdx.x;
    const size_t base = (size_t)row * DMODEL;
    float v[4];
    for (int e = 0; e < 4; ++e) v[e] = x[base + tid * 4 + e];
    float s1 = v[0] + v[1] + v[2] + v[3];
    float s2 = v[0]*v[0] + v[1]*v[1] + v[2]*v[2] + v[3]*v[3];
    for (int off = 32; off > 0; off >>= 1) {
        s1 += __shfl_down(s1, off);
        s2 += __shfl_down(s2, off);
    }
    __shared__ float red[8];
    int w = tid >> 6, lane = tid & 63;
    if (lane == 0) { red[w * 2] = s1; red[w * 2 + 1] = s2; }
    __syncthreads();
    if (tid == 0) {
        float a = 0.f, b = 0.f;
        for (int i = 0; i < 4; ++i) { a += red[2 * i]; b += red[2 * i + 1]; }
        red[0] = a; red[1] = b;
    }
    __syncthreads();
    s1 = red[0]; s2 = red[1];
    float mean = s1 * (1.0f / DMODEL);
    float var  = fmaxf((s2 - (float)DMODEL * mean * mean) * (1.0f / (DMODEL - 1)), 0.f);
    float inv  = 1.0f / (sqrtf(var) + 1e-6f);
    for (int e = 0; e < 4; ++e) {
        int c = tid * 4 + e;
        float y = alpha[c] * (v[e] - mean) * inv + beta[c];
        out[base + c] = __float2bfloat16(y);
    }
}

// ---------------- GEMM (double-buffered): C[M][N] = A @ Bt^T + bias ----------------
// EPI: 0 = bias -> bf16 ; 1 = bias+relu -> bf16 ; 2 = bias + f32 residual -> f32
template <int EPI>
__global__ __launch_bounds__(256) void gemm_bt(const __hip_bfloat16* __restrict__ A,
                                               const __hip_bfloat16* __restrict__ Bt,
                                               const float* __restrict__ bias,
                                               const float* __restrict__ res,
                                               void* __restrict__ Cout,
                                               int M, int N, int K) {
    __shared__ alignas(16) __hip_bfloat16 As[2][128 * 32];
    __shared__ alignas(16) __hip_bfloat16 Bs[2][128 * 32];
    const int tid = threadIdx.x, l = tid & 63;
    const int w = tid >> 6;
    const int wm = w >> 1, wn = w & 1, quad = l >> 4, lc = l & 15;
    const int row0 = blockIdx.y * 128, col0 = blockIdx.x * 128;
    const int srow = 32 * w + (l >> 2), scol = (l & 3) * 8;

    f32x4 acc[4][4];
    for (int i = 0; i < 4; ++i)
        for (int j = 0; j < 4; ++j) acc[i][j] = (f32x4){0.f, 0.f, 0.f, 0.f};

    // prologue: stage tile 0 into buffer 0
    for (int c = 0; c < 2; ++c) {
        async16(A  + (size_t)(row0 + srow + 16 * c) * K + scol, (char*)&As[0][0] + w * 2048 + c * 1024);
        async16(Bt + (size_t)(col0 + srow + 16 * c) * K + scol, (char*)&Bs[0][0] + w * 2048 + c * 1024);
    }
    const int NKT = K / 32;
    for (int kt = 0; kt < NKT; ++kt) {
        const int cur = kt & 1;
        __syncthreads();   // drains stage(kt); also fences prev-iter LDS reads
        if (kt + 1 < NKT) {
            const int k1 = (kt + 1) * 32;
            for (int c = 0; c < 2; ++c) {
                async16(A  + (size_t)(row0 + srow + 16 * c) * K + k1 + scol, (char*)&As[cur ^ 1][0] + w * 2048 + c * 1024);
                async16(Bt + (size_t)(col0 + srow + 16 * c) * K + k1 + scol, (char*)&Bs[cur ^ 1][0] + w * 2048 + c * 1024);
            }
        }
        bf16x8 af[4], bfr[4];
        for (int i = 0; i < 4; ++i) af[i]  = *(const bf16x8*)&As[cur][(64 * wm + 16 * i + lc) * 32 + quad * 8];
        for (int j = 0; j < 4; ++j) bfr[j] = *(const bf16x8*)&Bs[cur][(64 * wn + 16 * j + lc) * 32 + quad * 8];
        for (int i = 0; i < 4; ++i)
            for (int j = 0; j < 4; ++j)
                acc[i][j] = __builtin_amdgcn_mfma_f32_16x16x32_bf16(af[i], bfr[j], acc[i][j], 0, 0, 0);
    }

    __hip_bfloat16* Cb = (__hip_bfloat16*)Cout;
    float* Cf = (float*)Cout;
    for (int j = 0; j < 4; ++j) {
        int col = col0 + 64 * wn + 16 * j + lc;
        float bv = bias[col];
        for (int i = 0; i < 4; ++i) {
            int rbase = row0 + 64 * wm + 16 * i + quad * 4;
            for (int r = 0; r < 4; ++r) {
                size_t idx = (size_t)(rbase + r) * N + col;
                float vacc = acc[i][j][r] + bv;
                if (EPI == 0)      Cb[idx] = __float2bfloat16(vacc);
                else if (EPI == 1) Cb[idx] = __float2bfloat16(fmaxf(vacc, 0.f));
                else               Cf[idx] = vacc + res[idx];
            }
        }
    }
}

// ---------------- fused QKV GEMM (double-buffered): N = 3072 = [q | k | v] ----------------
// Segment = col0>>10 (block-uniform). seg 0 -> qb, seg 1 -> kb, seg 2 -> V^T per-head write.
__global__ __launch_bounds__(256) void gemm_qkv(const __hip_bfloat16* __restrict__ A,
                                                const __hip_bfloat16* __restrict__ Bt,
                                                const float* __restrict__ bq,
                                                const float* __restrict__ bk,
                                                const float* __restrict__ bv,
                                                __hip_bfloat16* __restrict__ qout,
                                                __hip_bfloat16* __restrict__ kout,
                                                __hip_bfloat16* __restrict__ vTout) {
    const int K = DMODEL;
    __shared__ alignas(16) __hip_bfloat16 As[2][128 * 32];
    __shared__ alignas(16) __hip_bfloat16 Bs[2][128 * 32];
    const int tid = threadIdx.x, l = tid & 63;
    const int w = tid >> 6;
    const int wm = w >> 1, wn = w & 1, quad = l >> 4, lc = l & 15;
    const int row0 = blockIdx.y * 128, col0 = blockIdx.x * 128;
    const int srow = 32 * w + (l >> 2), scol = (l & 3) * 8;

    f32x4 acc[4][4];
    for (int i = 0; i < 4; ++i)
        for (int j = 0; j < 4; ++j) acc[i][j] = (f32x4){0.f, 0.f, 0.f, 0.f};

    for (int c = 0; c < 2; ++c) {
        async16(A  + (size_t)(row0 + srow + 16 * c) * K + scol, (char*)&As[0][0] + w * 2048 + c * 1024);
        async16(Bt + (size_t)(col0 + srow + 16 * c) * K + scol, (char*)&Bs[0][0] + w * 2048 + c * 1024);
    }
    const int NKT = K / 32;
    for (int kt = 0; kt < NKT; ++kt) {
        const int cur = kt & 1;
        __syncthreads();
        if (kt + 1 < NKT) {
            const int k1 = (kt + 1) * 32;
            for (int c = 0; c < 2; ++c) {
                async16(A  + (size_t)(row0 + srow + 16 * c) * K + k1 + scol, (char*)&As[cur ^ 1][0] + w * 2048 + c * 1024);
                async16(Bt + (size_t)(col0 + srow + 16 * c) * K + k1 + scol, (char*)&Bs[cur ^ 1][0] + w * 2048 + c * 1024);
            }
        }
        bf16x8 af[4], bfr[4];
        for (int i = 0; i < 4; ++i) af[i]  = *(const bf16x8*)&As[cur][(64 * wm + 16 * i + lc) * 32 + quad * 8];
        for (int j = 0; j < 4; ++j) bfr[j] = *(const bf16x8*)&Bs[cur][(64 * wn + 16 * j + lc) * 32 + quad * 8];
        for (int i = 0; i < 4; ++i)
            for (int j = 0; j < 4; ++j)
                acc[i][j] = __builtin_amdgcn_mfma_f32_16x16x32_bf16(af[i], bfr[j], acc[i][j], 0, 0, 0);
    }

    const int seg = col0 >> 10;                       // block-uniform: 0=q, 1=k, 2=v
    const float* bias = (seg == 0) ? bq : (seg == 1) ? bk : bv;
    for (int j = 0; j < 4; ++j) {
        int col  = col0 + 64 * wn + 16 * j + lc;
        int colm = col & (DMODEL - 1);
        float bvx = bias[colm];
        for (int i = 0; i < 4; ++i) {
            int rbase = row0 + 64 * wm + 16 * i + quad * 4;
            for (int r = 0; r < 4; ++r) {
                int trow = rbase + r;
                float vacc = acc[i][j][r] + bvx;
                if (seg == 2) {
                    // V^T: token t=(b,s), colm=(h,d) -> [(b*NH+h)*HD+d][s]
                    int bb = trow >> 11, s = trow & (SEQ - 1);
                    int hh = colm >> 6, d = colm & (HD - 1);
                    vTout[((size_t)(bb * NH + hh) * HD + d) * SEQ + s] = __float2bfloat16(vacc);
                } else {
                    __hip_bfloat16* dst = (seg == 0) ? qout : kout;
                    dst[(size_t)trow * DMODEL + colm] = __float2bfloat16(vacc);
                }
            }
        }
    }
}

// ---------------- flash attention v8: swapped QK^T + in-register P redistribution ----------------
// Changes vs v7 (which was LDS-pipe-bound: 1.05e7 bank-conflict cycles + 48 volatile scalar
// LDS ops/wave-tile for the P round-trip):
//  * QK^T computed as mfma(K, Q) -> lane (quad,lc) holds P[q=lc][key=jn*16+quad*4+r] in regs.
//  * P -> bf16 pack + 2-stage butterfly (shfl_xor 32, shfl_xor 16) builds the PV A-fragments
//    in-register; the per-wave LDS P tile is deleted entirely (T12 pattern).
//  * K/V LDS tiles XOR-swizzled (block ^= (row>>1)&3) with PRE-SWIZZLED GLOBAL SOURCE addrs
//    (global_load_lds dest must stay linear — rule 21); ds_read_b128 frag reads de-conflicted.
//  * s_setprio(1) around MFMA clusters (T5; attn-positive per m191).
__global__ __launch_bounds__(256) void attn_kernel(const __hip_bfloat16* __restrict__ q,
                                                   const __hip_bfloat16* __restrict__ k,
                                                   const __hip_bfloat16* __restrict__ vT,
                                                   const int* __restrict__ mask,
                                                   __hip_bfloat16* __restrict__ ctx) {
    const int qt = blockIdx.x, bh = blockIdx.y;
    const int b = bh >> 4;
    const int q0 = qt * 128;
    const int tid = threadIdx.x, w = tid >> 6, l = tid & 63, quad = l >> 4, lc = l & 15;

    __shared__ alignas(16) __hip_bfloat16 Kh[2][2][64 * 32];   // [buf][half][64x32]
    __shared__ alignas(16) __hip_bfloat16 Vh[2][2][64 * 32];

    const size_t base   = (size_t)b * SEQ * DMODEL + (size_t)(bh & 15) * HD;
    const size_t vtbase = (size_t)bh * HD * SEQ;

    bf16x8 qf[2][2];
    for (int s = 0; s < 2; ++s) {
        const __hip_bfloat16* qrow = &q[base + (size_t)(q0 + s * 64 + w * 16 + lc) * DMODEL];
        qf[s][0] = *(const bf16x8*)&qrow[quad * 8];
        qf[s][1] = *(const bf16x8*)&qrow[32 + quad * 8];
    }

    f32x4 o[2][4];
    for (int s = 0; s < 2; ++s)
        for (int dj = 0; dj < 4; ++dj) o[s][dj] = (f32x4){0.f, 0.f, 0.f, 0.f};
    float rsp2[2] = {0.f, 0.f};

    const int lr  = l >> 2, cb = l & 3;
    const int cbsw = ((cb ^ ((lr >> 1) & 3))) * 8;   // pre-swizzled global source block (stage side)
    const int rsw  = (lc >> 1) & 3;                  // read-side XOR for row = jn*16+lc
    const int b1v = (l >> 5) & 1, b0v = (l >> 4) & 1;

    // prologue: stage tile 0 into buffer 0 (global source pre-swizzled; LDS dest linear)
    for (int c = 0; c < 2; ++c) {
        const int W = w * 2 + c;
        const int rr = (W & 3) * 16 + lr, cc8 = (W >> 2) * 32 + cbsw;
        async16(&k [base   + (size_t)rr * DMODEL + cc8], (char*)&Kh[0][0][0] + W * 1024);
        async16(&vT[vtbase + (size_t)rr * SEQ + cc8],    (char*)&Vh[0][0][0] + W * 1024);
    }

    const int NT = SEQ / 64;
    for (int kt = 0; kt < NT; ++kt) {
        const int k0 = kt * 64;
        const int cur = kt & 1;

        __syncthreads();   // drains stage(kt); fences prev-iter fragment reads
        if (kt + 1 < NT) {
            const int k1 = k0 + 64;
            for (int c = 0; c < 2; ++c) {
                const int W = w * 2 + c;
                const int rr = (W & 3) * 16 + lr, cc8 = (W >> 2) * 32 + cbsw;
                async16(&k [base   + (size_t)(k1 + rr) * DMODEL + cc8], (char*)&Kh[cur ^ 1][0][0] + W * 1024);
                async16(&vT[vtbase + (size_t)rr * SEQ + k1 + cc8],      (char*)&Vh[cur ^ 1][0][0] + W * 1024);
            }
        }
        // mask per key = k0 + jn*16 + quad*4 + r (16B-aligned int4 loads)
        int4 mc[4];
        for (int jn = 0; jn < 4; ++jn)
            mc[jn] = *(const int4*)&mask[b * SEQ + k0 + jn * 16 + quad * 4];

        bf16x8 kf0[4], kf1[4];
        for (int jn = 0; jn < 4; ++jn) {
            kf0[jn] = *(const bf16x8*)&Kh[cur][0][(jn * 16 + lc) * 32 + (quad ^ rsw) * 8];
            kf1[jn] = *(const bf16x8*)&Kh[cur][1][(jn * 16 + lc) * 32 + (quad ^ rsw) * 8];
        }
        bf16x8 vf0[4], vf1[4];
        for (int dj = 0; dj < 4; ++dj) {
            vf0[dj] = *(const bf16x8*)&Vh[cur][0][(dj * 16 + lc) * 32 + (quad ^ rsw) * 8];
            vf1[dj] = *(const bf16x8*)&Vh[cur][1][(dj * 16 + lc) * 32 + (quad ^ rsw) * 8];
        }

        for (int s = 0; s < 2; ++s) {
            // swapped QK^T: D[key][q] -> lane holds S[key=jn*16+quad*4+r][q=lc]
            f32x4 sa[4];
            __builtin_amdgcn_s_setprio(1);
            for (int jn = 0; jn < 4; ++jn) {
                f32x4 z = (f32x4){0.f, 0.f, 0.f, 0.f};
                z = __builtin_amdgcn_mfma_f32_16x16x32_bf16(kf0[jn], qf[s][0], z, 0, 0, 0);
                z = __builtin_amdgcn_mfma_f32_16x16x32_bf16(kf1[jn], qf[s][1], z, 0, 0, 0);
                sa[jn] = z;
            }
            __builtin_amdgcn_s_setprio(0);

            // softmax numerators + bf16 pair pack (key-adjacent pairs, lane-local)
            uint32 wd[4][2];
            float accs = 0.f;
            for (int jn = 0; jn < 4; ++jn) {
                float p0 = mc[jn].x ? __expf(sa[jn][0] * 0.125f) : 0.f;
                float p1 = mc[jn].y ? __expf(sa[jn][1] * 0.125f) : 0.f;
                float p2 = mc[jn].z ? __expf(sa[jn][2] * 0.125f) : 0.f;
                float p3 = mc[jn].w ? __expf(sa[jn][3] * 0.125f) : 0.f;
                accs += (p0 + p1) + (p2 + p3);
                __hip_bfloat16 h0 = __float2bfloat16(p0), h1 = __float2bfloat16(p1);
                __hip_bfloat16 h2 = __float2bfloat16(p2), h3 = __float2bfloat16(p3);
                wd[jn][0] = (uint32)*(unsigned short*)&h0 | ((uint32)*(unsigned short*)&h1 << 16);
                wd[jn][1] = (uint32)*(unsigned short*)&h2 | ((uint32)*(unsigned short*)&h3 << 16);
            }
            rsp2[s] += accs;

            // butterfly redistribution across quads -> PV A-fragments
            // word identity: (jn, p, src-quad). target quad = 2*(jn&1) + (src_quad>>1).
            uint32 send1[4], kept[4];
            send1[0] = b1v ? wd[0][0] : wd[1][0];  kept[0] = b1v ? wd[1][0] : wd[0][0];
            send1[1] = b1v ? wd[0][1] : wd[1][1];  kept[1] = b1v ? wd[1][1] : wd[0][1];
            send1[2] = b1v ? wd[2][0] : wd[3][0];  kept[2] = b1v ? wd[3][0] : wd[2][0];
            send1[3] = b1v ? wd[2][1] : wd[3][1];  kept[3] = b1v ? wd[3][1] : wd[2][1];
            uint32 recv1[4];
            for (int t = 0; t < 4; ++t) recv1[t] = (uint32)__shfl_xor((int)send1[t], 32);
            uint32 send2[4], stay[4];
            for (int t = 0; t < 4; ++t) {
                send2[t] = (b1v == b0v) ? recv1[t] : kept[t];
                stay[t]  = (b1v == b0v) ? kept[t]  : recv1[t];
            }
            uint32 recv2[4];
            for (int t = 0; t < 4; ++t) recv2[t] = (uint32)__shfl_xor((int)send2[t], 16);
            uint32 G0[4], G1[4];
            for (int t = 0; t < 4; ++t) {
                G0[t] = b0v ? recv2[t] : stay[t];
                G1[t] = b0v ? stay[t]  : recv2[t];
            }
            union { uint32 u[4]; bf16x8 v8; } pf0, pf1;
            pf0.u[0] = G0[0]; pf0.u[1] = G0[1]; pf0.u[2] = G1[0]; pf0.u[3] = G1[1];
            pf1.u[0] = G0[2]; pf1.u[1] = G0[3]; pf1.u[2] = G1[2]; pf1.u[3] = G1[3];

            __builtin_amdgcn_s_setprio(1);
            for (int dj = 0; dj < 4; ++dj) {
                o[s][dj] = __builtin_amdgcn_mfma_f32_16x16x32_bf16(pf0.v8, vf0[dj], o[s][dj], 0, 0, 0);
                o[s][dj] = __builtin_amdgcn_mfma_f32_16x16x32_bf16(pf1.v8, vf1[dj], o[s][dj], 0, 0, 0);
            }
            __builtin_amdgcn_s_setprio(0);
        }
    }

    for (int s = 0; s < 2; ++s) {
        // full row-sum for q = lc: reduce the lane-local partials across the 4 quads
        float rs = rsp2[s];
        rs += __shfl_xor(rs, 16);
        rs += __shfl_xor(rs, 32);
        for (int r = 0; r < 4; ++r) {
            // o-fragment row = quad*4+r; fetch that q-row's sum from a lane with lc == quad*4+r
            float rq = __shfl(rs, (l & 48) | (quad * 4 + r));
            float linv = 1.0f / rq;
            int row = q0 + s * 64 + w * 16 + quad * 4 + r;
            for (int dj = 0; dj < 4; ++dj)
                ctx[base + (size_t)row * DMODEL + dj * 16 + lc] = __float2bfloat16(o[s][dj][r] * linv);
        }
    }
}

// ---------------- launcher ----------------
extern "C" void kernel_launch(void* const* d_in, const int* in_sizes, int n_in,
                              void* d_out, int out_size, void* d_ws, size_t ws_size,
                              hipStream_t stream) {
    const float* x    = (const float*)d_in[0];
    const int*   mask = (const int*)d_in[1];
    const float* wq = (const float*)d_in[2];
    const float* bq = (const float*)d_in[3];
    const float* wk = (const float*)d_in[4];
    const float* bk = (const float*)d_in[5];
    const float* wv = (const float*)d_in[6];
    const float* bv = (const float*)d_in[7];
    const float* wo = (const float*)d_in[8];
    const float* bo = (const float*)d_in[9];
    const float* ln1_a = (const float*)d_in[10];
    const float* ln1_b = (const float*)d_in[11];
    const float* ln2_a = (const float*)d_in[12];
    const float* ln2_b = (const float*)d_in[13];
    const float* w1 = (const float*)d_in[14];
    const float* b1 = (const float*)d_in[15];
    const float* w2 = (const float*)d_in[16];
    const float* b2 = (const float*)d_in[17];
    float* out = (float*)d_out;

    char* ws = (char*)d_ws;
    const size_t SZ_WT  = (size_t)DMODEL * DMODEL * 2;   // 2 MB bf16
    const size_t SZ_ACT = (size_t)NTOK * DMODEL * 2;     // 8 MB bf16
    const size_t SZ_WF  = (size_t)FDIM * DMODEL * 2;     // 8 MB bf16
    size_t off = 0;
    __hip_bfloat16* wqkvT = (__hip_bfloat16*)(ws + off); off += 3 * SZ_WT;  // [3072][1024]
    __hip_bfloat16* woT   = (__hip_bfloat16*)(ws + off); off += SZ_WT;
    __hip_bfloat16* w1T   = (__hip_bfloat16*)(ws + off); off += SZ_WF;     // [F][D]
    __hip_bfloat16* w2T   = (__hip_bfloat16*)(ws + off); off += SZ_WF;     // [D][F]
    __hip_bfloat16* h1    = (__hip_bfloat16*)(ws + off); off += SZ_ACT;
    __hip_bfloat16* qb    = (__hip_bfloat16*)(ws + off); off += SZ_ACT;
    __hip_bfloat16* kb    = (__hip_bfloat16*)(ws + off); off += SZ_ACT;
    __hip_bfloat16* vTb   = (__hip_bfloat16*)(ws + off); off += SZ_ACT;    // V^T per head
    __hip_bfloat16* ctx   = (__hip_bfloat16*)(ws + off); off += SZ_ACT;
    float*          x1    = (float*)(ws + off);          off += (size_t)NTOK * DMODEL * 4;
    __hip_bfloat16* h2    = (__hip_bfloat16*)(ws + off); off += SZ_ACT;
    __hip_bfloat16* ff1   = h1;  // reuse h1 region after attention

    dim3 tb(32, 8);
    transpose_cvt_k<<<dim3(32, 32), tb, 0, stream>>>(wq, wqkvT,                   DMODEL, DMODEL);
    transpose_cvt_k<<<dim3(32, 32), tb, 0, stream>>>(wk, wqkvT + 1024 * DMODEL,   DMODEL, DMODEL);
    transpose_cvt_k<<<dim3(32, 32), tb, 0, stream>>>(wv, wqkvT + 2048 * DMODEL,   DMODEL, DMODEL);
    transpose_cvt_k<<<dim3(32, 32), tb, 0, stream>>>(wo, woT, DMODEL, DMODEL);
    transpose_cvt_k<<<dim3(128, 32), tb, 0, stream>>>(w1, w1T, DMODEL, FDIM);
    transpose_cvt_k<<<dim3(32, 128), tb, 0, stream>>>(w2, w2T, FDIM, DMODEL);

    ln_kernel<<<NTOK, 256, 0, stream>>>(x, ln1_a, ln1_b, h1);

    gemm_qkv<<<dim3(3 * DMODEL / 128, NTOK / 128), 256, 0, stream>>>(h1, wqkvT, bq, bk, bv, qb, kb, vTb);

    attn_kernel<<<dim3(SEQ / 128, NB * NH), 256, 0, stream>>>(qb, kb, vTb, mask, ctx);

    gemm_bt<2><<<dim3(DMODEL / 128, NTOK / 128), 256, 0, stream>>>(ctx, woT, bo, x, x1, NTOK, DMODEL, DMODEL);

    ln_kernel<<<NTOK, 256, 0, stream>>>(x1, ln2_a, ln2_b, h2);

    gemm_bt<1><<<dim3(FDIM / 128, NTOK / 128), 256, 0, stream>>>(h2, w1T, b1, nullptr, ff1, NTOK, FDIM, DMODEL);
    gemm_bt<2><<<dim3(DMODEL / 128, NTOK / 128), 256, 0, stream>>>(ff1, w2T, b2, x1, out, NTOK, DMODEL, FDIM);
}

// Round 2
// 400.405 us; speedup vs baseline: 1.1332x; 1.0692x over previous
//
#include <hip/hip_runtime.h>
#include <hip/hip_bf16.h>

typedef __attribute__((ext_vector_type(8))) short bf16x8;   // 8 bf16 in 4 VGPRs
typedef __attribute__((ext_vector_type(4))) float f32x4;
typedef unsigned int uint32;

#define DMODEL 1024
#define SEQ    2048
#define NB     2
#define NH     16
#define HD     64
#define FDIM   4096
#define NTOK   (NB*SEQ)   // 4096

// ---------------- async global->LDS (wave-uniform LDS base + lane*16) ----------------
__device__ __forceinline__ void async16(const void* g, void* s) {
    __builtin_amdgcn_global_load_lds((const __attribute__((address_space(1))) unsigned int*)g,
                                     (__attribute__((address_space(3))) unsigned int*)s,
                                     16, 0, 0);
}

// ---------------- transpose + f32->bf16 convert: src[R][C] f32 -> dst[C][R] bf16 ----------------
__global__ __launch_bounds__(256) void transpose_cvt_k(const float* __restrict__ src,
                                                       __hip_bfloat16* __restrict__ dst,
                                                       int R, int C) {
    __shared__ __hip_bfloat16 tile[32][33];
    int tx = threadIdx.x, ty = threadIdx.y;
    int bx = blockIdx.x * 32, by = blockIdx.y * 32;
    for (int i = 0; i < 32; i += 8)
        tile[ty + i][tx] = __float2bfloat16(src[(size_t)(by + ty + i) * C + bx + tx]);
    __syncthreads();
    for (int i = 0; i < 32; i += 8)
        dst[(size_t)(bx + ty + i) * R + by + tx] = tile[tx][ty + i];
}

// ---------------- layernorm: f32 row of 1024, unbiased std (ddof=1), /(std+eps) -> bf16 ----------------
__global__ __launch_bounds__(256) void ln_kernel(const float* __restrict__ x,
                                                 const float* __restrict__ alpha,
                                                 const float* __restrict__ beta,
                                                 __hip_bfloat16* __restrict__ out) {
    const int row = blockIdx.x, tid = threadIdx.x;
    const size_t base = (size_t)row * DMODEL;
    float v[4];
    for (int e = 0; e < 4; ++e) v[e] = x[base + tid * 4 + e];
    float s1 = v[0] + v[1] + v[2] + v[3];
    float s2 = v[0]*v[0] + v[1]*v[1] + v[2]*v[2] + v[3]*v[3];
    for (int off = 32; off > 0; off >>= 1) {
        s1 += __shfl_down(s1, off);
        s2 += __shfl_down(s2, off);
    }
    __shared__ float red[8];
    int w = tid >> 6, lane = tid & 63;
    if (lane == 0) { red[w * 2] = s1; red[w * 2 + 1] = s2; }
    __syncthreads();
    if (tid == 0) {
        float a = 0.f, b = 0.f;
        for (int i = 0; i < 4; ++i) { a += red[2 * i]; b += red[2 * i + 1]; }
        red[0] = a; red[1] = b;
    }
    __syncthreads();
    s1 = red[0]; s2 = red[1];
    float mean = s1 * (1.0f / DMODEL);
    float var  = fmaxf((s2 - (float)DMODEL * mean * mean) * (1.0f / (DMODEL - 1)), 0.f);
    float inv  = 1.0f / (sqrtf(var) + 1e-6f);
    for (int e = 0; e < 4; ++e) {
        int c = tid * 4 + e;
        float y = alpha[c] * (v[e] - mean) * inv + beta[c];
        out[base + c] = __float2bfloat16(y);
    }
}

// ---------------- GEMM (double-buffered, T2-swizzled): C[M][N] = A @ Bt^T + bias ----------------
// EPI: 0 = bias -> bf16 ; 1 = bias+relu -> bf16 ; 2 = bias + f32 residual -> f32
// LDS chunk swizzle: physical 16B chunk p of row r holds logical chunk p ^ ((r>>1)&3).
// Stage side pre-swizzles the GLOBAL source chunk (LDS dest of global_load_lds stays linear);
// read side applies quad ^ ((lc>>1)&3). 8-way ds_read_b128 conflict -> 2-way (free).
template <int EPI>
__global__ __launch_bounds__(256) void gemm_bt(const __hip_bfloat16* __restrict__ A,
                                               const __hip_bfloat16* __restrict__ Bt,
                                               const float* __restrict__ bias,
                                               const float* __restrict__ res,
                                               void* __restrict__ Cout,
                                               int M, int N, int K) {
    __shared__ alignas(16) __hip_bfloat16 As[2][128 * 32];
    __shared__ alignas(16) __hip_bfloat16 Bs[2][128 * 32];
    const int tid = threadIdx.x, l = tid & 63;
    const int w = tid >> 6;
    const int wm = w >> 1, wn = w & 1, quad = l >> 4, lc = l & 15;
    const int row0 = blockIdx.y * 128, col0 = blockIdx.x * 128;
    const int lr = l >> 2, cb = l & 3;
    const int srow = 32 * w + lr;
    const int scol = (cb ^ ((lr >> 1) & 3)) * 8;     // pre-swizzled global source chunk
    const int rsw  = (lc >> 1) & 3;                  // read-side un-swizzle

    f32x4 acc[4][4];
    for (int i = 0; i < 4; ++i)
        for (int j = 0; j < 4; ++j) acc[i][j] = (f32x4){0.f, 0.f, 0.f, 0.f};

    // prologue: stage tile 0 into buffer 0
    for (int c = 0; c < 2; ++c) {
        async16(A  + (size_t)(row0 + srow + 16 * c) * K + scol, (char*)&As[0][0] + w * 2048 + c * 1024);
        async16(Bt + (size_t)(col0 + srow + 16 * c) * K + scol, (char*)&Bs[0][0] + w * 2048 + c * 1024);
    }
    const int NKT = K / 32;
    for (int kt = 0; kt < NKT; ++kt) {
        const int cur = kt & 1;
        __syncthreads();   // drains stage(kt); also fences prev-iter LDS reads
        if (kt + 1 < NKT) {
            const int k1 = (kt + 1) * 32;
            for (int c = 0; c < 2; ++c) {
                async16(A  + (size_t)(row0 + srow + 16 * c) * K + k1 + scol, (char*)&As[cur ^ 1][0] + w * 2048 + c * 1024);
                async16(Bt + (size_t)(col0 + srow + 16 * c) * K + k1 + scol, (char*)&Bs[cur ^ 1][0] + w * 2048 + c * 1024);
            }
        }
        bf16x8 af[4], bfr[4];
        for (int i = 0; i < 4; ++i) af[i]  = *(const bf16x8*)&As[cur][(64 * wm + 16 * i + lc) * 32 + (quad ^ rsw) * 8];
        for (int j = 0; j < 4; ++j) bfr[j] = *(const bf16x8*)&Bs[cur][(64 * wn + 16 * j + lc) * 32 + (quad ^ rsw) * 8];
        for (int i = 0; i < 4; ++i)
            for (int j = 0; j < 4; ++j)
                acc[i][j] = __builtin_amdgcn_mfma_f32_16x16x32_bf16(af[i], bfr[j], acc[i][j], 0, 0, 0);
    }

    __hip_bfloat16* Cb = (__hip_bfloat16*)Cout;
    float* Cf = (float*)Cout;
    for (int j = 0; j < 4; ++j) {
        int col = col0 + 64 * wn + 16 * j + lc;
        float bv = bias[col];
        for (int i = 0; i < 4; ++i) {
            int rbase = row0 + 64 * wm + 16 * i + quad * 4;
            for (int r = 0; r < 4; ++r) {
                size_t idx = (size_t)(rbase + r) * N + col;
                float vacc = acc[i][j][r] + bv;
                if (EPI == 0)      Cb[idx] = __float2bfloat16(vacc);
                else if (EPI == 1) Cb[idx] = __float2bfloat16(fmaxf(vacc, 0.f));
                else               Cf[idx] = vacc + res[idx];
            }
        }
    }
}

// ---------------- in-block split-K GEMM for small-N shapes (N=1024 -> 256 blocks = 1/CU) ----------------
// 512 threads = 8 waves: group g = w>>2 computes K-half g. Each group has a private
// double-buffered LDS pair (64 KB total). After the K loop the whole 64 KB is repurposed
// as a 128x128 f32 combine tile: group1 writes its acc, group0 adds + does the epilogue.
// Doubles waves/SIMD (1 -> 2) and halves barrier count per unit work for grid-limited shapes.
template <int EPI>
__global__ __launch_bounds__(512) void gemm_bt_sk(const __hip_bfloat16* __restrict__ A,
                                                  const __hip_bfloat16* __restrict__ Bt,
                                                  const float* __restrict__ bias,
                                                  const float* __restrict__ res,
                                                  void* __restrict__ Cout,
                                                  int M, int N, int K) {
    __shared__ alignas(16) char smem[65536];   // [As: 2g x 2buf x 8KB][Bs: same]
    const int tid = threadIdx.x, l = tid & 63;
    const int w = tid >> 6;           // 0..7
    const int g = w >> 2;             // K-group
    const int wl = w & 3;             // wave within group
    const int wm = wl >> 1, wn = wl & 1, quad = l >> 4, lc = l & 15;
    const int row0 = blockIdx.y * 128, col0 = blockIdx.x * 128;
    const int lr = l >> 2, cb = l & 3;
    const int srow = 32 * wl + lr;
    const int scol = (cb ^ ((lr >> 1) & 3)) * 8;
    const int rsw  = (lc >> 1) & 3;
    const int Kh = K >> 1;
    const int kbase = g * Kh;

    char* AsBase = smem + (size_t)g * 16384;
    char* BsBase = smem + 32768 + (size_t)g * 16384;

    f32x4 acc[4][4];
    for (int i = 0; i < 4; ++i)
        for (int j = 0; j < 4; ++j) acc[i][j] = (f32x4){0.f, 0.f, 0.f, 0.f};

    // prologue: stage tile 0 into buffer 0 (per group)
    for (int c = 0; c < 2; ++c) {
        async16(A  + (size_t)(row0 + srow + 16 * c) * K + kbase + scol, AsBase + wl * 2048 + c * 1024);
        async16(Bt + (size_t)(col0 + srow + 16 * c) * K + kbase + scol, BsBase + wl * 2048 + c * 1024);
    }
    const int NKT = Kh / 32;
    for (int kt = 0; kt < NKT; ++kt) {
        const int cur = kt & 1;
        __syncthreads();
        if (kt + 1 < NKT) {
            const int k1 = kbase + (kt + 1) * 32;
            for (int c = 0; c < 2; ++c) {
                async16(A  + (size_t)(row0 + srow + 16 * c) * K + k1 + scol, AsBase + (cur ^ 1) * 8192 + wl * 2048 + c * 1024);
                async16(Bt + (size_t)(col0 + srow + 16 * c) * K + k1 + scol, BsBase + (cur ^ 1) * 8192 + wl * 2048 + c * 1024);
            }
        }
        const __hip_bfloat16* Asc = (const __hip_bfloat16*)(AsBase + cur * 8192);
        const __hip_bfloat16* Bsc = (const __hip_bfloat16*)(BsBase + cur * 8192);
        bf16x8 af[4], bfr[4];
        for (int i = 0; i < 4; ++i) af[i]  = *(const bf16x8*)&Asc[(64 * wm + 16 * i + lc) * 32 + (quad ^ rsw) * 8];
        for (int j = 0; j < 4; ++j) bfr[j] = *(const bf16x8*)&Bsc[(64 * wn + 16 * j + lc) * 32 + (quad ^ rsw) * 8];
        for (int i = 0; i < 4; ++i)
            for (int j = 0; j < 4; ++j)
                acc[i][j] = __builtin_amdgcn_mfma_f32_16x16x32_bf16(af[i], bfr[j], acc[i][j], 0, 0, 0);
    }

    // combine: repurpose the whole 64 KB as a 128x128 f32 tile
    __syncthreads();                       // all LDS reads + staged loads drained
    float* comb = (float*)smem;
    if (g == 1) {
        for (int j = 0; j < 4; ++j) {
            int col = 64 * wn + 16 * j + lc;
            int ccol = col ^ ((quad & 1) << 4);          // 2-way-max bank spread
            for (int i = 0; i < 4; ++i) {
                int rb = 64 * wm + 16 * i + quad * 4;
                for (int r = 0; r < 4; ++r)
                    comb[(rb + r) * 128 + ccol] = acc[i][j][r];
            }
        }
    }
    __syncthreads();
    if (g == 0) {
        __hip_bfloat16* Cb = (__hip_bfloat16*)Cout;
        float* Cf = (float*)Cout;
        for (int j = 0; j < 4; ++j) {
            int coll = 64 * wn + 16 * j + lc;
            int ccol = coll ^ ((quad & 1) << 4);
            int col  = col0 + coll;
            float bv = bias[col];
            for (int i = 0; i < 4; ++i) {
                int rbl = 64 * wm + 16 * i + quad * 4;
                for (int r = 0; r < 4; ++r) {
                    size_t idx = (size_t)(row0 + rbl + r) * N + col;
                    float vacc = acc[i][j][r] + comb[(rbl + r) * 128 + ccol] + bv;
                    if (EPI == 0)      Cb[idx] = __float2bfloat16(vacc);
                    else if (EPI == 1) Cb[idx] = __float2bfloat16(fmaxf(vacc, 0.f));
                    else               Cf[idx] = vacc + res[idx];
                }
            }
        }
    }
}

// ---------------- fused QKV GEMM (double-buffered, T2-swizzled): N = 3072 = [q | k | v] ----------------
__global__ __launch_bounds__(256) void gemm_qkv(const __hip_bfloat16* __restrict__ A,
                                                const __hip_bfloat16* __restrict__ Bt,
                                                const float* __restrict__ bq,
                                                const float* __restrict__ bk,
                                                const float* __restrict__ bv,
                                                __hip_bfloat16* __restrict__ qout,
                                                __hip_bfloat16* __restrict__ kout,
                                                __hip_bfloat16* __restrict__ vTout) {
    const int K = DMODEL;
    __shared__ alignas(16) __hip_bfloat16 As[2][128 * 32];
    __shared__ alignas(16) __hip_bfloat16 Bs[2][128 * 32];
    const int tid = threadIdx.x, l = tid & 63;
    const int w = tid >> 6;
    const int wm = w >> 1, wn = w & 1, quad = l >> 4, lc = l & 15;
    const int row0 = blockIdx.y * 128, col0 = blockIdx.x * 128;
    const int lr = l >> 2, cb = l & 3;
    const int srow = 32 * w + lr;
    const int scol = (cb ^ ((lr >> 1) & 3)) * 8;
    const int rsw  = (lc >> 1) & 3;

    f32x4 acc[4][4];
    for (int i = 0; i < 4; ++i)
        for (int j = 0; j < 4; ++j) acc[i][j] = (f32x4){0.f, 0.f, 0.f, 0.f};

    for (int c = 0; c < 2; ++c) {
        async16(A  + (size_t)(row0 + srow + 16 * c) * K + scol, (char*)&As[0][0] + w * 2048 + c * 1024);
        async16(Bt + (size_t)(col0 + srow + 16 * c) * K + scol, (char*)&Bs[0][0] + w * 2048 + c * 1024);
    }
    const int NKT = K / 32;
    for (int kt = 0; kt < NKT; ++kt) {
        const int cur = kt & 1;
        __syncthreads();
        if (kt + 1 < NKT) {
            const int k1 = (kt + 1) * 32;
            for (int c = 0; c < 2; ++c) {
                async16(A  + (size_t)(row0 + srow + 16 * c) * K + k1 + scol, (char*)&As[cur ^ 1][0] + w * 2048 + c * 1024);
                async16(Bt + (size_t)(col0 + srow + 16 * c) * K + k1 + scol, (char*)&Bs[cur ^ 1][0] + w * 2048 + c * 1024);
            }
        }
        bf16x8 af[4], bfr[4];
        for (int i = 0; i < 4; ++i) af[i]  = *(const bf16x8*)&As[cur][(64 * wm + 16 * i + lc) * 32 + (quad ^ rsw) * 8];
        for (int j = 0; j < 4; ++j) bfr[j] = *(const bf16x8*)&Bs[cur][(64 * wn + 16 * j + lc) * 32 + (quad ^ rsw) * 8];
        for (int i = 0; i < 4; ++i)
            for (int j = 0; j < 4; ++j)
                acc[i][j] = __builtin_amdgcn_mfma_f32_16x16x32_bf16(af[i], bfr[j], acc[i][j], 0, 0, 0);
    }

    const int seg = col0 >> 10;                       // block-uniform: 0=q, 1=k, 2=v
    const float* bias = (seg == 0) ? bq : (seg == 1) ? bk : bv;
    for (int j = 0; j < 4; ++j) {
        int col  = col0 + 64 * wn + 16 * j + lc;
        int colm = col & (DMODEL - 1);
        float bvx = bias[colm];
        for (int i = 0; i < 4; ++i) {
            int rbase = row0 + 64 * wm + 16 * i + quad * 4;
            for (int r = 0; r < 4; ++r) {
                int trow = rbase + r;
                float vacc = acc[i][j][r] + bvx;
                if (seg == 2) {
                    // V^T: token t=(b,s), colm=(h,d) -> [(b*NH+h)*HD+d][s]
                    int bb = trow >> 11, s = trow & (SEQ - 1);
                    int hh = colm >> 6, d = colm & (HD - 1);
                    vTout[((size_t)(bb * NH + hh) * HD + d) * SEQ + s] = __float2bfloat16(vacc);
                } else {
                    __hip_bfloat16* dst = (seg == 0) ? qout : kout;
                    dst[(size_t)trow * DMODEL + colm] = __float2bfloat16(vacc);
                }
            }
        }
    }
}

// ---------------- flash attention v8: swapped QK^T + in-register P redistribution ----------------
__global__ __launch_bounds__(256) void attn_kernel(const __hip_bfloat16* __restrict__ q,
                                                   const __hip_bfloat16* __restrict__ k,
                                                   const __hip_bfloat16* __restrict__ vT,
                                                   const int* __restrict__ mask,
                                                   __hip_bfloat16* __restrict__ ctx) {
    const int qt = blockIdx.x, bh = blockIdx.y;
    const int b = bh >> 4;
    const int q0 = qt * 128;
    const int tid = threadIdx.x, w = tid >> 6, l = tid & 63, quad = l >> 4, lc = l & 15;

    __shared__ alignas(16) __hip_bfloat16 Kh[2][2][64 * 32];   // [buf][half][64x32]
    __shared__ alignas(16) __hip_bfloat16 Vh[2][2][64 * 32];

    const size_t base   = (size_t)b * SEQ * DMODEL + (size_t)(bh & 15) * HD;
    const size_t vtbase = (size_t)bh * HD * SEQ;

    bf16x8 qf[2][2];
    for (int s = 0; s < 2; ++s) {
        const __hip_bfloat16* qrow = &q[base + (size_t)(q0 + s * 64 + w * 16 + lc) * DMODEL];
        qf[s][0] = *(const bf16x8*)&qrow[quad * 8];
        qf[s][1] = *(const bf16x8*)&qrow[32 + quad * 8];
    }

    f32x4 o[2][4];
    for (int s = 0; s < 2; ++s)
        for (int dj = 0; dj < 4; ++dj) o[s][dj] = (f32x4){0.f, 0.f, 0.f, 0.f};
    float rsp2[2] = {0.f, 0.f};

    const int lr  = l >> 2, cb = l & 3;
    const int cbsw = ((cb ^ ((lr >> 1) & 3))) * 8;   // pre-swizzled global source block (stage side)
    const int rsw  = (lc >> 1) & 3;                  // read-side XOR
    const int b1v = (l >> 5) & 1, b0v = (l >> 4) & 1;

    // prologue: stage tile 0 into buffer 0 (global source pre-swizzled; LDS dest linear)
    for (int c = 0; c < 2; ++c) {
        const int W = w * 2 + c;
        const int rr = (W & 3) * 16 + lr, cc8 = (W >> 2) * 32 + cbsw;
        async16(&k [base   + (size_t)rr * DMODEL + cc8], (char*)&Kh[0][0][0] + W * 1024);
        async16(&vT[vtbase + (size_t)rr * SEQ + cc8],    (char*)&Vh[0][0][0] + W * 1024);
    }

    const int NT = SEQ / 64;
    for (int kt = 0; kt < NT; ++kt) {
        const int k0 = kt * 64;
        const int cur = kt & 1;

        __syncthreads();   // drains stage(kt); fences prev-iter fragment reads
        if (kt + 1 < NT) {
            const int k1 = k0 + 64;
            for (int c = 0; c < 2; ++c) {
                const int W = w * 2 + c;
                const int rr = (W & 3) * 16 + lr, cc8 = (W >> 2) * 32 + cbsw;
                async16(&k [base   + (size_t)(k1 + rr) * DMODEL + cc8], (char*)&Kh[cur ^ 1][0][0] + W * 1024);
                async16(&vT[vtbase + (size_t)rr * SEQ + k1 + cc8],      (char*)&Vh[cur ^ 1][0][0] + W * 1024);
            }
        }
        // mask per key = k0 + jn*16 + quad*4 + r (16B-aligned int4 loads)
        int4 mc[4];
        for (int jn = 0; jn < 4; ++jn)
            mc[jn] = *(const int4*)&mask[b * SEQ + k0 + jn * 16 + quad * 4];

        bf16x8 kf0[4], kf1[4];
        for (int jn = 0; jn < 4; ++jn) {
            kf0[jn] = *(const bf16x8*)&Kh[cur][0][(jn * 16 + lc) * 32 + (quad ^ rsw) * 8];
            kf1[jn] = *(const bf16x8*)&Kh[cur][1][(jn * 16 + lc) * 32 + (quad ^ rsw) * 8];
        }
        bf16x8 vf0[4], vf1[4];
        for (int dj = 0; dj < 4; ++dj) {
            vf0[dj] = *(const bf16x8*)&Vh[cur][0][(dj * 16 + lc) * 32 + (quad ^ rsw) * 8];
            vf1[dj] = *(const bf16x8*)&Vh[cur][1][(dj * 16 + lc) * 32 + (quad ^ rsw) * 8];
        }

        for (int s = 0; s < 2; ++s) {
            // swapped QK^T: D[key][q] -> lane holds S[key=jn*16+quad*4+r][q=lc]
            f32x4 sa[4];
            __builtin_amdgcn_s_setprio(1);
            for (int jn = 0; jn < 4; ++jn) {
                f32x4 z = (f32x4){0.f, 0.f, 0.f, 0.f};
                z = __builtin_amdgcn_mfma_f32_16x16x32_bf16(kf0[jn], qf[s][0], z, 0, 0, 0);
                z = __builtin_amdgcn_mfma_f32_16x16x32_bf16(kf1[jn], qf[s][1], z, 0, 0, 0);
                sa[jn] = z;
            }
            __builtin_amdgcn_s_setprio(0);

            // softmax numerators + bf16 pair pack (key-adjacent pairs, lane-local)
            uint32 wd[4][2];
            float accs = 0.f;
            for (int jn = 0; jn < 4; ++jn) {
                float p0 = mc[jn].x ? __expf(sa[jn][0] * 0.125f) : 0.f;
                float p1 = mc[jn].y ? __expf(sa[jn][1] * 0.125f) : 0.f;
                float p2 = mc[jn].z ? __expf(sa[jn][2] * 0.125f) : 0.f;
                float p3 = mc[jn].w ? __expf(sa[jn][3] * 0.125f) : 0.f;
                accs += (p0 + p1) + (p2 + p3);
                __hip_bfloat16 h0 = __float2bfloat16(p0), h1 = __float2bfloat16(p1);
                __hip_bfloat16 h2 = __float2bfloat16(p2), h3 = __float2bfloat16(p3);
                wd[jn][0] = (uint32)*(unsigned short*)&h0 | ((uint32)*(unsigned short*)&h1 << 16);
                wd[jn][1] = (uint32)*(unsigned short*)&h2 | ((uint32)*(unsigned short*)&h3 << 16);
            }
            rsp2[s] += accs;

            // butterfly redistribution across quads -> PV A-fragments
            uint32 send1[4], kept[4];
            send1[0] = b1v ? wd[0][0] : wd[1][0];  kept[0] = b1v ? wd[1][0] : wd[0][0];
            send1[1] = b1v ? wd[0][1] : wd[1][1];  kept[1] = b1v ? wd[1][1] : wd[0][1];
            send1[2] = b1v ? wd[2][0] : wd[3][0];  kept[2] = b1v ? wd[3][0] : wd[2][0];
            send1[3] = b1v ? wd[2][1] : wd[3][1];  kept[3] = b1v ? wd[3][1] : wd[2][1];
            uint32 recv1[4];
            for (int t = 0; t < 4; ++t) recv1[t] = (uint32)__shfl_xor((int)send1[t], 32);
            uint32 send2[4], stay[4];
            for (int t = 0; t < 4; ++t) {
                send2[t] = (b1v == b0v) ? recv1[t] : kept[t];
                stay[t]  = (b1v == b0v) ? kept[t]  : recv1[t];
            }
            uint32 recv2[4];
            for (int t = 0; t < 4; ++t) recv2[t] = (uint32)__shfl_xor((int)send2[t], 16);
            uint32 G0[4], G1[4];
            for (int t = 0; t < 4; ++t) {
                G0[t] = b0v ? recv2[t] : stay[t];
                G1[t] = b0v ? stay[t]  : recv2[t];
            }
            union { uint32 u[4]; bf16x8 v8; } pf0, pf1;
            pf0.u[0] = G0[0]; pf0.u[1] = G0[1]; pf0.u[2] = G1[0]; pf0.u[3] = G1[1];
            pf1.u[0] = G0[2]; pf1.u[1] = G0[3]; pf1.u[2] = G1[2]; pf1.u[3] = G1[3];

            __builtin_amdgcn_s_setprio(1);
            for (int dj = 0; dj < 4; ++dj) {
                o[s][dj] = __builtin_amdgcn_mfma_f32_16x16x32_bf16(pf0.v8, vf0[dj], o[s][dj], 0, 0, 0);
                o[s][dj] = __builtin_amdgcn_mfma_f32_16x16x32_bf16(pf1.v8, vf1[dj], o[s][dj], 0, 0, 0);
            }
            __builtin_amdgcn_s_setprio(0);
        }
    }

    for (int s = 0; s < 2; ++s) {
        float rs = rsp2[s];
        rs += __shfl_xor(rs, 16);
        rs += __shfl_xor(rs, 32);
        for (int r = 0; r < 4; ++r) {
            float rq = __shfl(rs, (l & 48) | (quad * 4 + r));
            float linv = 1.0f / rq;
            int row = q0 + s * 64 + w * 16 + quad * 4 + r;
            for (int dj = 0; dj < 4; ++dj)
                ctx[base + (size_t)row * DMODEL + dj * 16 + lc] = __float2bfloat16(o[s][dj][r] * linv);
        }
    }
}

// ---------------- launcher ----------------
extern "C" void kernel_launch(void* const* d_in, const int* in_sizes, int n_in,
                              void* d_out, int out_size, void* d_ws, size_t ws_size,
                              hipStream_t stream) {
    const float* x    = (const float*)d_in[0];
    const int*   mask = (const int*)d_in[1];
    const float* wq = (const float*)d_in[2];
    const float* bq = (const float*)d_in[3];
    const float* wk = (const float*)d_in[4];
    const float* bk = (const float*)d_in[5];
    const float* wv = (const float*)d_in[6];
    const float* bv = (const float*)d_in[7];
    const float* wo = (const float*)d_in[8];
    const float* bo = (const float*)d_in[9];
    const float* ln1_a = (const float*)d_in[10];
    const float* ln1_b = (const float*)d_in[11];
    const float* ln2_a = (const float*)d_in[12];
    const float* ln2_b = (const float*)d_in[13];
    const float* w1 = (const float*)d_in[14];
    const float* b1 = (const float*)d_in[15];
    const float* w2 = (const float*)d_in[16];
    const float* b2 = (const float*)d_in[17];
    float* out = (float*)d_out;

    char* ws = (char*)d_ws;
    const size_t SZ_WT  = (size_t)DMODEL * DMODEL * 2;   // 2 MB bf16
    const size_t SZ_ACT = (size_t)NTOK * DMODEL * 2;     // 8 MB bf16
    const size_t SZ_WF  = (size_t)FDIM * DMODEL * 2;     // 8 MB bf16
    size_t off = 0;
    __hip_bfloat16* wqkvT = (__hip_bfloat16*)(ws + off); off += 3 * SZ_WT;  // [3072][1024]
    __hip_bfloat16* woT   = (__hip_bfloat16*)(ws + off); off += SZ_WT;
    __hip_bfloat16* w1T   = (__hip_bfloat16*)(ws + off); off += SZ_WF;     // [F][D]
    __hip_bfloat16* w2T   = (__hip_bfloat16*)(ws + off); off += SZ_WF;     // [D][F]
    __hip_bfloat16* h1    = (__hip_bfloat16*)(ws + off); off += SZ_ACT;
    __hip_bfloat16* qb    = (__hip_bfloat16*)(ws + off); off += SZ_ACT;
    __hip_bfloat16* kb    = (__hip_bfloat16*)(ws + off); off += SZ_ACT;
    __hip_bfloat16* vTb   = (__hip_bfloat16*)(ws + off); off += SZ_ACT;    // V^T per head
    __hip_bfloat16* ctx   = (__hip_bfloat16*)(ws + off); off += SZ_ACT;
    float*          x1    = (float*)(ws + off);          off += (size_t)NTOK * DMODEL * 4;
    __hip_bfloat16* h2    = (__hip_bfloat16*)(ws + off); off += SZ_ACT;
    __hip_bfloat16* ff1   = h1;  // reuse h1 region after attention

    dim3 tb(32, 8);
    transpose_cvt_k<<<dim3(32, 32), tb, 0, stream>>>(wq, wqkvT,                   DMODEL, DMODEL);
    transpose_cvt_k<<<dim3(32, 32), tb, 0, stream>>>(wk, wqkvT + 1024 * DMODEL,   DMODEL, DMODEL);
    transpose_cvt_k<<<dim3(32, 32), tb, 0, stream>>>(wv, wqkvT + 2048 * DMODEL,   DMODEL, DMODEL);
    transpose_cvt_k<<<dim3(32, 32), tb, 0, stream>>>(wo, woT, DMODEL, DMODEL);
    transpose_cvt_k<<<dim3(128, 32), tb, 0, stream>>>(w1, w1T, DMODEL, FDIM);
    transpose_cvt_k<<<dim3(32, 128), tb, 0, stream>>>(w2, w2T, FDIM, DMODEL);

    ln_kernel<<<NTOK, 256, 0, stream>>>(x, ln1_a, ln1_b, h1);

    gemm_qkv<<<dim3(3 * DMODEL / 128, NTOK / 128), 256, 0, stream>>>(h1, wqkvT, bq, bk, bv, qb, kb, vTb);

    attn_kernel<<<dim3(SEQ / 128, NB * NH), 256, 0, stream>>>(qb, kb, vTb, mask, ctx);

    gemm_bt_sk<2><<<dim3(DMODEL / 128, NTOK / 128), 512, 0, stream>>>(ctx, woT, bo, x, x1, NTOK, DMODEL, DMODEL);

    ln_kernel<<<NTOK, 256, 0, stream>>>(x1, ln2_a, ln2_b, h2);

    gemm_bt<1><<<dim3(FDIM / 128, NTOK / 128), 256, 0, stream>>>(h2, w1T, b1, nullptr, ff1, NTOK, FDIM, DMODEL);
    gemm_bt_sk<2><<<dim3(DMODEL / 128, NTOK / 128), 512, 0, stream>>>(ff1, w2T, b2, x1, out, NTOK, DMODEL, FDIM);
}